// Round 8
// baseline (130.641 us; speedup 1.0000x reference)
//
#include <hip/hip_runtime.h>
#include <math.h>

#define D_DIM 128
#define A_DIM 128
#define NTHREADS 512      // 8 waves; one block per segment
#define WPS 8             // independent wave-workers per segment

typedef _Float16 f16x8 __attribute__((ext_vector_type(8)));
typedef __attribute__((ext_vector_type(4))) float f32x4;

__device__ __forceinline__ float fast_tanh(float v) {
    float e = __expf(2.0f * v);
    return 1.0f - 2.0f * __builtin_amdgcn_rcpf(e + 1.0f);
}

__device__ __forceinline__ int lower_bound_i32(const int* __restrict__ arr, int n, int val) {
    int lo = 0, hi = n;
    while (lo < hi) {
        int mid = (lo + hi) >> 1;
        if (arr[mid] < val) lo = mid + 1; else hi = mid;
    }
    return lo;
}

// Fully fused, barrier-free main loop, NO-MAX softmax:
//   scores s bounded by sum|W2| * max|tanh| ~ 9  ->  exp(s) in [1e-4, 8e3],
//   so accumulate o += exp(s)*x, den += exp(s) unnormalized (fp32-safe),
//   normalize once at the end. Weight ratios identical to the max-shifted
//   reference, so accuracy is unchanged.
// Each of the 8 waves is an independent worker over 16-row tiles (strided by
// 8 tiles); zero LDS / zero barriers / zero cross-wave traffic in the loop.
// scores via fp16 2-term-split MFMA (x = ah+al fp16, W1 fp16); b2 cancels.
extern "C" __global__ void __launch_bounds__(NTHREADS)
fused_attn_kernel(const float* __restrict__ x,
                  const int* __restrict__ bidx,
                  const float* __restrict__ W1,
                  const float* __restrict__ b1,
                  const float* __restrict__ W2,
                  float* __restrict__ out,
                  int N, int B)
{
    __shared__ _Float16 w1s[A_DIM * D_DIM];   // 32 KB, [col][k] XOR-swizzled
    __shared__ float sB1[A_DIM];
    __shared__ float sW2[A_DIM];
    __shared__ float o_red[8 * 4 * 32];       // 4 KB epilogue reduce
    __shared__ float s_d[8];
    __shared__ int   seg_bounds[2];

    const int tid = threadIdx.x;
    const int b   = blockIdx.x;

    if (tid == 0) {
        seg_bounds[0] = lower_bound_i32(bidx, N, b);
        seg_bounds[1] = lower_bound_i32(bidx, N, b + 1);
    }
    if (tid < A_DIM) { sB1[tid] = b1[tid]; sW2[tid] = W2[tid]; }

    // stage W1: read coalesced [k][c], write transposed+swizzled fp16
    for (int item = tid; item < A_DIM * 16; item += NTHREADS) {
        const int c = item & (A_DIM - 1);
        const int chunk = item >> 7;          // 16B chunk along k (0..15)
        f16x8 vh;
        #pragma unroll
        for (int j = 0; j < 8; ++j)
            vh[j] = (_Float16)W1[(chunk * 8 + j) * A_DIM + c];
        const int addr = c * 256 + ((chunk ^ (c & 15)) << 4);
        *reinterpret_cast<f16x8*>(reinterpret_cast<char*>(w1s) + addr) = vh;
    }
    __syncthreads();

    const int lo  = seg_bounds[0];
    const int len = seg_bounds[1] - lo;

    if (len <= 0) {
        if (tid < D_DIM) out[b * D_DIM + tid] = 0.0f;
        return;
    }

    const int lane = tid & 63;
    const int wv   = tid >> 6;          // wave id = worker id
    const int lc   = lane & 15;         // row within 16-row tile
    const int lg   = lane >> 4;         // 0..3 ; k-group / reg group
    const int nt   = (len + 15) >> 4;   // 16-row tiles in segment

    float den = 0.0f;                   // unnormalized sum of exp(s) (per wave)
    float o_part[32];                   // unnormalized weighted x (dims ks*32+lg*8+j)
    #pragma unroll
    for (int v = 0; v < 32; ++v) o_part[v] = 0.0f;

    float4 buf[8];
    if (wv < nt) {   // prologue: this wave's first tile
        const int gi = min(lo + wv * 16 + lc, N - 1);
        const float4* xr = reinterpret_cast<const float4*>(x + (size_t)gi * D_DIM);
        #pragma unroll
        for (int ks = 0; ks < 4; ++ks) {
            buf[2*ks]   = xr[ks*8 + lg*2];
            buf[2*ks+1] = xr[ks*8 + lg*2 + 1];
        }
    }

    for (int tile = wv; tile < nt; tile += WPS) {
        // split buf -> fp16 hi/lo fragments (k = ks*32 + lg*8 + j)
        f16x8 ah[4], al[4];
        #pragma unroll
        for (int ks = 0; ks < 4; ++ks) {
            #pragma unroll
            for (int j = 0; j < 8; ++j) {
                const float xv = (j < 4) ? ((const float*)&buf[2*ks])[j]
                                         : ((const float*)&buf[2*ks+1])[j-4];
                const _Float16 h = (_Float16)xv;
                ah[ks][j] = h;
                al[ks][j] = (_Float16)(xv - (float)h);
            }
        }

        // prefetch this wave's next tile; nothing force-drains it
        const int next = tile + WPS;
        if (next < nt) {
            const int gi = min(lo + next * 16 + lc, N - 1);
            const float4* xr = reinterpret_cast<const float4*>(x + (size_t)gi * D_DIM);
            #pragma unroll
            for (int ks = 0; ks < 4; ++ks) {
                buf[2*ks]   = xr[ks*8 + lg*2];
                buf[2*ks+1] = xr[ks*8 + lg*2 + 1];
            }
        }

        // ---- scores via MFMA: this wave's 16 rows x 128 cols ----
        float part0 = 0.f, part1 = 0.f, part2 = 0.f, part3 = 0.f;
        #pragma unroll
        for (int t = 0; t < 8; ++t) {
            f32x4 acc = {0.f, 0.f, 0.f, 0.f};
            const int c = t * 16 + lc;
            const char* base = reinterpret_cast<const char*>(w1s) + c * 256;
            #pragma unroll
            for (int ks = 0; ks < 4; ++ks) {
                const int chunk = ks * 4 + lg;
                f16x8 bh = *reinterpret_cast<const f16x8*>(
                    base + ((chunk ^ (c & 15)) << 4));
                acc = __builtin_amdgcn_mfma_f32_16x16x32_f16(ah[ks], bh, acc, 0, 0, 0);
                acc = __builtin_amdgcn_mfma_f32_16x16x32_f16(al[ks], bh, acc, 0, 0, 0);
            }
            const float b1v = sB1[c], w2v = sW2[c];
            part0 += fast_tanh(acc[0] + b1v) * w2v;
            part1 += fast_tanh(acc[1] + b1v) * w2v;
            part2 += fast_tanh(acc[2] + b1v) * w2v;
            part3 += fast_tanh(acc[3] + b1v) * w2v;
        }
        // reduce over 16 lc lanes -> lane group lg holds scores of rows lg*4+r
        #pragma unroll
        for (int mk = 8; mk >= 1; mk >>= 1) {
            part0 += __shfl_xor(part0, mk);
            part1 += __shfl_xor(part1, mk);
            part2 += __shfl_xor(part2, mk);
            part3 += __shfl_xor(part3, mk);
        }
        // this thread's own-row (row = lc) score: lane lg'=(lc>>2), reg lc&3
        const int src = (lc >> 2) << 4;
        const float t0 = __shfl(part0, src);
        const float t1 = __shfl(part1, src);
        const float t2 = __shfl(part2, src);
        const float t3 = __shfl(part3, src);
        const float s01 = (lc & 1) ? t1 : t0;
        const float s23 = (lc & 1) ? t3 : t2;
        const float my_s = (lc & 2) ? s23 : s01;
        // weight: exp(score), no max shift (|s| <= sum|W2| ~ 9, fp32-safe)
        const float w = (tile * 16 + lc < len) ? __expf(my_s) : 0.0f;
        den += w;

        // ---- accumulate unnormalized weighted x from in-register frags ----
        #pragma unroll
        for (int ks = 0; ks < 4; ++ks) {
            #pragma unroll
            for (int j = 0; j < 8; ++j) {
                const int v = ks * 8 + j;
                o_part[v] = fmaf(w, (float)ah[ks][j] + (float)al[ks][j], o_part[v]);
            }
        }
    }

    // ---- epilogue (single barrier): merge 8 independent waves ----
    // o_part: reduce over the 16 lc lanes (they hold disjoint rows' products
    // for the same dim slice); den: reduce over lc lanes only (each row is
    // replicated across the 4 lg groups, so masks 1,2,4,8 count each row once)
    #pragma unroll
    for (int v = 0; v < 32; ++v) {
        #pragma unroll
        for (int mk = 8; mk >= 1; mk >>= 1)
            o_part[v] += __shfl_xor(o_part[v], mk);
    }
    #pragma unroll
    for (int mk = 8; mk >= 1; mk >>= 1) den += __shfl_xor(den, mk);

    if (lc == 0) {
        #pragma unroll
        for (int v = 0; v < 32; ++v)
            o_red[(wv * 4 + lg) * 32 + v] = o_part[v];
        if (lg == 0) s_d[wv] = den;
    }
    __syncthreads();

    if (tid < 128) {
        const int lg2 = tid >> 5, v = tid & 31;
        float val = 0.0f;
        #pragma unroll
        for (int w2 = 0; w2 < 8; ++w2) val += o_red[(w2 * 4 + lg2) * 32 + v];
        float dtot = 0.0f;
        #pragma unroll
        for (int w2 = 0; w2 < 8; ++w2) dtot += s_d[w2];
        const int d = (v >> 3) * 32 + lg2 * 8 + (v & 7);
        out[b * D_DIM + d] = val / dtot;
    }
}

extern "C" void kernel_launch(void* const* d_in, const int* in_sizes, int n_in,
                              void* d_out, int out_size, void* d_ws, size_t ws_size,
                              hipStream_t stream)
{
    const float* x    = (const float*)d_in[0];
    const int*   bidx = (const int*)d_in[1];
    const float* W1   = (const float*)d_in[2];
    const float* b1   = (const float*)d_in[3];
    const float* W2   = (const float*)d_in[4];
    // d_in[5] = b2: cancels in softmax, unused

    const int N = in_sizes[1];
    const int B = out_size / D_DIM;

    fused_attn_kernel<<<B, NTHREADS, 0, stream>>>(
        x, bidx, W1, b1, W2, (float*)d_out, N, B);
}

// Round 9
// 105.323 us; speedup vs baseline: 1.2404x; 1.2404x over previous
//
#include <hip/hip_runtime.h>
#include <math.h>

#define D_DIM 128
#define A_DIM 128
#define SPLIT 4            // blocks per segment
#define NTHREADS 256       // 4 waves per block
#define NWAVES 4
#define WPS (SPLIT * NWAVES)   // 16 independent wave-workers per segment
#define PSTRIDE 132        // floats per partial record: o[128], den, pad

typedef _Float16 f16x8 __attribute__((ext_vector_type(8)));
typedef __attribute__((ext_vector_type(4))) float f32x4;

__device__ __forceinline__ float fast_tanh(float v) {
    float e = __expf(2.0f * v);
    return 1.0f - 2.0f * __builtin_amdgcn_rcpf(e + 1.0f);
}

__device__ __forceinline__ int lower_bound_i32(const int* __restrict__ arr, int n, int val) {
    int lo = 0, hi = n;
    while (lo < hi) {
        int mid = (lo + hi) >> 1;
        if (arr[mid] < val) lo = mid + 1; else hi = mid;
    }
    return lo;
}

// K0: parallel segment bounds (bidx sorted)
extern "C" __global__ void __launch_bounds__(256)
seg_bounds_kernel(const int* __restrict__ bidx, int N, int B,
                  int* __restrict__ seg_start)
{
    const int i = blockIdx.x * 256 + threadIdx.x;
    if (i <= B) seg_start[i] = lower_bound_i32(bidx, N, i);
}

// K1: per-(segment, quarter) UNNORMALIZED partial, barrier-free main loop.
// No-max softmax: |s| <= sum|W2|*max|tanh| ~ 9 -> exp(s) fp32-safe; accumulate
// o += exp(s)*x, den += exp(s); combine = plain sum across quarters.
// Each wave is an independent worker over 16-row tiles (stride WPS).
// scores via fp16 2-term-split MFMA (x = ah+al fp16, W1 fp16); b2 cancels.
// 4-wave blocks + grid B*4 -> up to 4 blocks/CU (R7 was 1 block/CU, 22% occ).
// Split uses explicit named scalars: local init-list arrays caused scratch
// traffic (R7: 27 MB WRITE_SIZE vs 0.13 MB of real writes).
extern "C" __global__ void __launch_bounds__(NTHREADS)
fused_partial_kernel(const float* __restrict__ x,
                     const int* __restrict__ seg_start,
                     const float* __restrict__ W1,
                     const float* __restrict__ b1,
                     const float* __restrict__ W2,
                     float* __restrict__ part,
                     int N)
{
    __shared__ _Float16 w1s[A_DIM * D_DIM];   // 32 KB, [col][k] XOR-swizzled
    __shared__ float sB1[A_DIM];
    __shared__ float sW2[A_DIM];
    __shared__ float o_red[NWAVES * 4 * 32];  // 2 KB epilogue reduce
    __shared__ float s_d[NWAVES];

    const int tid = threadIdx.x;
    const int b   = blockIdx.x >> 2;          // segment  (SPLIT = 4)
    const int q   = blockIdx.x & (SPLIT - 1); // quarter

    if (tid < A_DIM) { sB1[tid] = b1[tid]; sW2[tid] = W2[tid]; }

    // stage W1: read coalesced [k][c], write transposed+swizzled fp16
    for (int item = tid; item < A_DIM * 16; item += NTHREADS) {
        const int c = item & (A_DIM - 1);
        const int chunk = item >> 7;          // 16B chunk along k (0..15)
        f16x8 vh;
        #pragma unroll
        for (int j = 0; j < 8; ++j)
            vh[j] = (_Float16)W1[(chunk * 8 + j) * A_DIM + c];
        const int addr = c * 256 + ((chunk ^ (c & 15)) << 4);
        *reinterpret_cast<f16x8*>(reinterpret_cast<char*>(w1s) + addr) = vh;
    }
    __syncthreads();

    const int lo  = seg_start[b];
    const int len = seg_start[b + 1] - lo;
    const int nt  = (len + 15) >> 4;          // 16-row tiles in segment

    const int lane = tid & 63;
    const int wv   = tid >> 6;
    const int lc   = lane & 15;               // row within 16-row tile
    const int lg   = lane >> 4;               // 0..3 ; k-group
    const int wk   = q * NWAVES + wv;         // worker id 0..15

    float den = 0.0f;
    float o_part[32];                         // dims ks*32 + lg*8 + j
    #pragma unroll
    for (int v = 0; v < 32; ++v) o_part[v] = 0.0f;

    float4 buf[8];
    if (wk < nt) {   // prologue: this wave's first tile
        const int gi = min(lo + wk * 16 + lc, N - 1);
        const float4* xr = reinterpret_cast<const float4*>(x + (size_t)gi * D_DIM);
        #pragma unroll
        for (int ks = 0; ks < 4; ++ks) {
            buf[2*ks]   = xr[ks*8 + lg*2];
            buf[2*ks+1] = xr[ks*8 + lg*2 + 1];
        }
    }

    for (int tile = wk; tile < nt; tile += WPS) {
        // split buf -> fp16 hi/lo fragments, explicit scalars (no local array)
        f16x8 ah[4], al[4];
        #pragma unroll
        for (int ks = 0; ks < 4; ++ks) {
            const float4 v0 = buf[2*ks];
            const float4 v1 = buf[2*ks+1];
            _Float16 h;
            h = (_Float16)v0.x; ah[ks][0] = h; al[ks][0] = (_Float16)(v0.x - (float)h);
            h = (_Float16)v0.y; ah[ks][1] = h; al[ks][1] = (_Float16)(v0.y - (float)h);
            h = (_Float16)v0.z; ah[ks][2] = h; al[ks][2] = (_Float16)(v0.z - (float)h);
            h = (_Float16)v0.w; ah[ks][3] = h; al[ks][3] = (_Float16)(v0.w - (float)h);
            h = (_Float16)v1.x; ah[ks][4] = h; al[ks][4] = (_Float16)(v1.x - (float)h);
            h = (_Float16)v1.y; ah[ks][5] = h; al[ks][5] = (_Float16)(v1.y - (float)h);
            h = (_Float16)v1.z; ah[ks][6] = h; al[ks][6] = (_Float16)(v1.z - (float)h);
            h = (_Float16)v1.w; ah[ks][7] = h; al[ks][7] = (_Float16)(v1.w - (float)h);
        }

        // prefetch this wave's next tile (no barrier will drain it)
        const int next = tile + WPS;
        if (next < nt) {
            const int gi = min(lo + next * 16 + lc, N - 1);
            const float4* xr = reinterpret_cast<const float4*>(x + (size_t)gi * D_DIM);
            #pragma unroll
            for (int ks = 0; ks < 4; ++ks) {
                buf[2*ks]   = xr[ks*8 + lg*2];
                buf[2*ks+1] = xr[ks*8 + lg*2 + 1];
            }
        }

        // ---- scores via MFMA: this wave's 16 rows x 128 cols ----
        float part0 = 0.f, part1 = 0.f, part2 = 0.f, part3 = 0.f;
        #pragma unroll
        for (int t = 0; t < 8; ++t) {
            f32x4 acc = {0.f, 0.f, 0.f, 0.f};
            const int c = t * 16 + lc;
            const char* base = reinterpret_cast<const char*>(w1s) + c * 256;
            #pragma unroll
            for (int ks = 0; ks < 4; ++ks) {
                const int chunk = ks * 4 + lg;
                f16x8 bh = *reinterpret_cast<const f16x8*>(
                    base + ((chunk ^ (c & 15)) << 4));
                acc = __builtin_amdgcn_mfma_f32_16x16x32_f16(ah[ks], bh, acc, 0, 0, 0);
                acc = __builtin_amdgcn_mfma_f32_16x16x32_f16(al[ks], bh, acc, 0, 0, 0);
            }
            const float b1v = sB1[c], w2v = sW2[c];
            part0 += fast_tanh(acc[0] + b1v) * w2v;
            part1 += fast_tanh(acc[1] + b1v) * w2v;
            part2 += fast_tanh(acc[2] + b1v) * w2v;
            part3 += fast_tanh(acc[3] + b1v) * w2v;
        }
        // reduce over 16 lc lanes -> lane group lg holds rows lg*4+r
        #pragma unroll
        for (int mk = 8; mk >= 1; mk >>= 1) {
            part0 += __shfl_xor(part0, mk);
            part1 += __shfl_xor(part1, mk);
            part2 += __shfl_xor(part2, mk);
            part3 += __shfl_xor(part3, mk);
        }
        // own-row (row = lc) score: from lane (lc>>2)*16, reg lc&3
        const int src = (lc >> 2) << 4;
        const float t0 = __shfl(part0, src);
        const float t1 = __shfl(part1, src);
        const float t2 = __shfl(part2, src);
        const float t3 = __shfl(part3, src);
        const float s01 = (lc & 1) ? t1 : t0;
        const float s23 = (lc & 1) ? t3 : t2;
        const float my_s = (lc & 2) ? s23 : s01;
        const float w = (tile * 16 + lc < len) ? __expf(my_s) : 0.0f;
        den += w;

        // ---- accumulate unnormalized weighted x from in-register frags ----
        #pragma unroll
        for (int ks = 0; ks < 4; ++ks) {
            #pragma unroll
            for (int j = 0; j < 8; ++j) {
                const int v = ks * 8 + j;
                o_part[v] = fmaf(w, (float)ah[ks][j] + (float)al[ks][j], o_part[v]);
            }
        }
    }

    // ---- epilogue (single barrier): merge this block's 4 waves ----
    #pragma unroll
    for (int v = 0; v < 32; ++v) {
        #pragma unroll
        for (int mk = 8; mk >= 1; mk >>= 1)
            o_part[v] += __shfl_xor(o_part[v], mk);
    }
    #pragma unroll
    for (int mk = 8; mk >= 1; mk >>= 1) den += __shfl_xor(den, mk);

    if (lc == 0) {
        #pragma unroll
        for (int v = 0; v < 32; ++v)
            o_red[(wv * 4 + lg) * 32 + v] = o_part[v];
        if (lg == 0) s_d[wv] = den;
    }
    __syncthreads();

    float* pb = part + (size_t)blockIdx.x * PSTRIDE;
    if (tid < 128) {
        const int lg2 = tid >> 5, v = tid & 31;
        float val = 0.0f;
        #pragma unroll
        for (int w2 = 0; w2 < NWAVES; ++w2) val += o_red[(w2 * 4 + lg2) * 32 + v];
        const int d = (v >> 3) * 32 + lg2 * 8 + (v & 7);
        pb[d] = val;
        if (tid == 0)
            pb[128] = s_d[0] + s_d[1] + s_d[2] + s_d[3];
    }
}

// K2: sum SPLIT unnormalized partials per segment, normalize.
extern "C" __global__ void __launch_bounds__(128)
combine_kernel(const float* __restrict__ part, float* __restrict__ out)
{
    const int b = blockIdx.x, d = threadIdx.x;
    const float* pb = part + (size_t)b * SPLIT * PSTRIDE;

    float den = 0.0f, val = 0.0f;
    #pragma unroll
    for (int q = 0; q < SPLIT; ++q) {
        den += pb[q * PSTRIDE + 128];
        val += pb[q * PSTRIDE + d];
    }
    out[b * D_DIM + d] = (den > 0.0f) ? val / den : 0.0f;
}

extern "C" void kernel_launch(void* const* d_in, const int* in_sizes, int n_in,
                              void* d_out, int out_size, void* d_ws, size_t ws_size,
                              hipStream_t stream)
{
    const float* x    = (const float*)d_in[0];
    const int*   bidx = (const int*)d_in[1];
    const float* W1   = (const float*)d_in[2];
    const float* b1   = (const float*)d_in[3];
    const float* W2   = (const float*)d_in[4];
    // d_in[5] = b2: cancels in softmax, unused

    const int N = in_sizes[1];
    const int B = out_size / D_DIM;

    char* ws = (char*)d_ws;
    int*   seg_start = (int*)ws;                       // B+1 ints
    float* part      = (float*)(ws + 4096);            // B*SPLIT*PSTRIDE floats

    seg_bounds_kernel<<<(B + 256) / 256, 256, 0, stream>>>(bidx, N, B, seg_start);
    fused_partial_kernel<<<B * SPLIT, NTHREADS, 0, stream>>>(
        x, seg_start, W1, b1, W2, part, N);
    combine_kernel<<<B, 128, 0, stream>>>(part, (float*)d_out);
}

// Round 10
// 89.051 us; speedup vs baseline: 1.4670x; 1.1827x over previous
//
#include <hip/hip_runtime.h>
#include <math.h>

#define D_DIM 128
#define A_DIM 128
#define SPLIT 4            // contiguous quarters per segment
#define NTHREADS 256       // 4 waves per block
#define NWAVES 4
#define PSTRIDE 132        // floats per partial record: o[128], den, pad

typedef _Float16 f16x8 __attribute__((ext_vector_type(8)));
typedef __attribute__((ext_vector_type(4))) float f32x4;

__device__ __forceinline__ float fast_tanh(float v) {
    float e = __expf(2.0f * v);
    return 1.0f - 2.0f * __builtin_amdgcn_rcpf(e + 1.0f);
}

__device__ __forceinline__ int lower_bound_i32(const int* __restrict__ arr, int n, int val) {
    int lo = 0, hi = n;
    while (lo < hi) {
        int mid = (lo + hi) >> 1;
        if (arr[mid] < val) lo = mid + 1; else hi = mid;
    }
    return lo;
}

// K0: parallel segment bounds (bidx sorted)
extern "C" __global__ void __launch_bounds__(256)
seg_bounds_kernel(const int* __restrict__ bidx, int N, int B,
                  int* __restrict__ seg_start)
{
    const int i = blockIdx.x * 256 + threadIdx.x;
    if (i <= B) seg_start[i] = lower_bound_i32(bidx, N, i);
}

// K1: per-(segment, CONTIGUOUS quarter) unnormalized partial, barrier-free.
// No-max softmax (|s| <~ 9 -> exp fp32-safe); o += exp(s)*x, den += exp(s).
// Block q owns rows [lo+q*qper, lo+q*qper+qper): its 4 waves sweep adjacent
// 16-row strips of contiguous 64-row tiles -> sequential HBM streams per
// block (R8's 16-row interleave across blocks shredded locality: 105us).
// Own-row score via per-wave LDS slot (same-wave ds dep, no barrier) instead
// of R8's 4x variable-src bpermute chain.
extern "C" __global__ void __launch_bounds__(NTHREADS)
fused_partial_kernel(const float* __restrict__ x,
                     const int* __restrict__ seg_start,
                     const float* __restrict__ W1,
                     const float* __restrict__ b1,
                     const float* __restrict__ W2,
                     float* __restrict__ part,
                     int N)
{
    __shared__ _Float16 w1s[A_DIM * D_DIM];   // 32 KB, [col][k] XOR-swizzled
    __shared__ float sB1[A_DIM];
    __shared__ float sW2[A_DIM];
    __shared__ float s_sc[NWAVES * 16];       // per-wave own-row score slots
    __shared__ float o_red[NWAVES * 4 * 32];  // 2 KB epilogue reduce
    __shared__ float s_d[NWAVES];

    const int tid = threadIdx.x;
    const int b   = blockIdx.x >> 2;          // segment  (SPLIT = 4)
    const int q   = blockIdx.x & (SPLIT - 1); // quarter

    if (tid < A_DIM) { sB1[tid] = b1[tid]; sW2[tid] = W2[tid]; }

    // stage W1: read coalesced [k][c], write transposed+swizzled fp16
    for (int item = tid; item < A_DIM * 16; item += NTHREADS) {
        const int c = item & (A_DIM - 1);
        const int chunk = item >> 7;          // 16B chunk along k (0..15)
        f16x8 vh;
        #pragma unroll
        for (int j = 0; j < 8; ++j)
            vh[j] = (_Float16)W1[(chunk * 8 + j) * A_DIM + c];
        const int addr = c * 256 + ((chunk ^ (c & 15)) << 4);
        *reinterpret_cast<f16x8*>(reinterpret_cast<char*>(w1s) + addr) = vh;
    }
    __syncthreads();

    const int lo  = seg_start[b];
    const int len = seg_start[b + 1] - lo;
    // contiguous quarter: rows [q0, q0+qper) of the segment (local coords)
    const int qper = (((len + SPLIT - 1) / SPLIT) + 63) & ~63;
    const int q0   = q * qper;
    const int qlen = min(qper, len - q0);     // may be <= 0
    const int ntl  = (qlen + 63) >> 6;        // 64-row tiles in this quarter

    const int lane = tid & 63;
    const int wv   = tid >> 6;
    const int lc   = lane & 15;               // row within 16-row strip
    const int lg   = lane >> 4;               // 0..3 ; k-group
    const int rowoff = q0 + wv * 16 + lc;     // local row this thread handles at t=0

    float den = 0.0f;
    float o_part[32];                         // dims ks*32 + lg*8 + j
    #pragma unroll
    for (int v = 0; v < 32; ++v) o_part[v] = 0.0f;

    float4 buf[8];
    if (ntl > 0) {   // prologue: first tile
        const int gi = min(lo + rowoff, N - 1);
        const float4* xr = reinterpret_cast<const float4*>(x + (size_t)gi * D_DIM);
        #pragma unroll
        for (int ks = 0; ks < 4; ++ks) {
            buf[2*ks]   = xr[ks*8 + lg*2];
            buf[2*ks+1] = xr[ks*8 + lg*2 + 1];
        }
    }

    for (int t = 0; t < ntl; ++t) {
        // split buf -> fp16 hi/lo fragments, explicit named scalars
        f16x8 ah[4], al[4];
        #pragma unroll
        for (int ks = 0; ks < 4; ++ks) {
            const float4 v0 = buf[2*ks];
            const float4 v1 = buf[2*ks+1];
            _Float16 h;
            h = (_Float16)v0.x; ah[ks][0] = h; al[ks][0] = (_Float16)(v0.x - (float)h);
            h = (_Float16)v0.y; ah[ks][1] = h; al[ks][1] = (_Float16)(v0.y - (float)h);
            h = (_Float16)v0.z; ah[ks][2] = h; al[ks][2] = (_Float16)(v0.z - (float)h);
            h = (_Float16)v0.w; ah[ks][3] = h; al[ks][3] = (_Float16)(v0.w - (float)h);
            h = (_Float16)v1.x; ah[ks][4] = h; al[ks][4] = (_Float16)(v1.x - (float)h);
            h = (_Float16)v1.y; ah[ks][5] = h; al[ks][5] = (_Float16)(v1.y - (float)h);
            h = (_Float16)v1.z; ah[ks][6] = h; al[ks][6] = (_Float16)(v1.z - (float)h);
            h = (_Float16)v1.w; ah[ks][7] = h; al[ks][7] = (_Float16)(v1.w - (float)h);
        }

        // prefetch next contiguous tile (no barrier ever drains it)
        if (t + 1 < ntl) {
            const int gi = min(lo + rowoff + (t + 1) * 64, N - 1);
            const float4* xr = reinterpret_cast<const float4*>(x + (size_t)gi * D_DIM);
            #pragma unroll
            for (int ks = 0; ks < 4; ++ks) {
                buf[2*ks]   = xr[ks*8 + lg*2];
                buf[2*ks+1] = xr[ks*8 + lg*2 + 1];
            }
        }

        // ---- scores via MFMA: this wave's 16 rows x 128 cols ----
        __builtin_amdgcn_s_setprio(1);
        float part0 = 0.f, part1 = 0.f, part2 = 0.f, part3 = 0.f;
        #pragma unroll
        for (int tt = 0; tt < 8; ++tt) {
            f32x4 acc = {0.f, 0.f, 0.f, 0.f};
            const int c = tt * 16 + lc;
            const char* base = reinterpret_cast<const char*>(w1s) + c * 256;
            #pragma unroll
            for (int ks = 0; ks < 4; ++ks) {
                const int chunk = ks * 4 + lg;
                f16x8 bh = *reinterpret_cast<const f16x8*>(
                    base + ((chunk ^ (c & 15)) << 4));
                acc = __builtin_amdgcn_mfma_f32_16x16x32_f16(ah[ks], bh, acc, 0, 0, 0);
                acc = __builtin_amdgcn_mfma_f32_16x16x32_f16(al[ks], bh, acc, 0, 0, 0);
            }
            const float b1v = sB1[c], w2v = sW2[c];
            part0 += fast_tanh(acc[0] + b1v) * w2v;
            part1 += fast_tanh(acc[1] + b1v) * w2v;
            part2 += fast_tanh(acc[2] + b1v) * w2v;
            part3 += fast_tanh(acc[3] + b1v) * w2v;
        }
        __builtin_amdgcn_s_setprio(0);

        // reduce over 16 lc lanes -> every lane of group lg holds rows lg*4+r
        #pragma unroll
        for (int mk = 8; mk >= 1; mk >>= 1) {
            part0 += __shfl_xor(part0, mk);
            part1 += __shfl_xor(part1, mk);
            part2 += __shfl_xor(part2, mk);
            part3 += __shfl_xor(part3, mk);
        }
        // own-row score via per-wave LDS slot (same-wave write->read)
        if (lc == 0) {
            float* sl = &s_sc[wv * 16 + lg * 4];
            sl[0] = part0; sl[1] = part1; sl[2] = part2; sl[3] = part3;
        }
        const float my_s = s_sc[wv * 16 + lc];
        const float w = (rowoff + t * 64 < len) ? __expf(my_s) : 0.0f;
        den += w;

        // ---- accumulate unnormalized weighted x from in-register frags ----
        #pragma unroll
        for (int ks = 0; ks < 4; ++ks) {
            #pragma unroll
            for (int j = 0; j < 8; ++j) {
                const int v = ks * 8 + j;
                o_part[v] = fmaf(w, (float)ah[ks][j] + (float)al[ks][j], o_part[v]);
            }
        }
    }

    // ---- epilogue (single barrier): merge this block's 4 waves ----
    #pragma unroll
    for (int v = 0; v < 32; ++v) {
        #pragma unroll
        for (int mk = 8; mk >= 1; mk >>= 1)
            o_part[v] += __shfl_xor(o_part[v], mk);
    }
    #pragma unroll
    for (int mk = 8; mk >= 1; mk >>= 1) den += __shfl_xor(den, mk);

    if (lc == 0) {
        #pragma unroll
        for (int v = 0; v < 32; ++v)
            o_red[(wv * 4 + lg) * 32 + v] = o_part[v];
        if (lg == 0) s_d[wv] = den;
    }
    __syncthreads();

    float* pb = part + (size_t)blockIdx.x * PSTRIDE;
    if (tid < 128) {
        const int lg2 = tid >> 5, v = tid & 31;
        float val = 0.0f;
        #pragma unroll
        for (int w2 = 0; w2 < NWAVES; ++w2) val += o_red[(w2 * 4 + lg2) * 32 + v];
        const int d = (v >> 3) * 32 + lg2 * 8 + (v & 7);
        pb[d] = val;
        if (tid == 0)
            pb[128] = s_d[0] + s_d[1] + s_d[2] + s_d[3];
    }
}

// K2: sum SPLIT unnormalized partials per segment, normalize.
extern "C" __global__ void __launch_bounds__(128)
combine_kernel(const float* __restrict__ part, float* __restrict__ out)
{
    const int b = blockIdx.x, d = threadIdx.x;
    const float* pb = part + (size_t)b * SPLIT * PSTRIDE;

    float den = 0.0f, val = 0.0f;
    #pragma unroll
    for (int q = 0; q < SPLIT; ++q) {
        den += pb[q * PSTRIDE + 128];
        val += pb[q * PSTRIDE + d];
    }
    out[b * D_DIM + d] = (den > 0.0f) ? val / den : 0.0f;
}

extern "C" void kernel_launch(void* const* d_in, const int* in_sizes, int n_in,
                              void* d_out, int out_size, void* d_ws, size_t ws_size,
                              hipStream_t stream)
{
    const float* x    = (const float*)d_in[0];
    const int*   bidx = (const int*)d_in[1];
    const float* W1   = (const float*)d_in[2];
    const float* b1   = (const float*)d_in[3];
    const float* W2   = (const float*)d_in[4];
    // d_in[5] = b2: cancels in softmax, unused

    const int N = in_sizes[1];
    const int B = out_size / D_DIM;

    char* ws = (char*)d_ws;
    int*   seg_start = (int*)ws;                       // B+1 ints
    float* part      = (float*)(ws + 4096);            // B*SPLIT*PSTRIDE floats

    seg_bounds_kernel<<<(B + 256) / 256, 256, 0, stream>>>(bidx, N, B, seg_start);
    fused_partial_kernel<<<B * SPLIT, NTHREADS, 0, stream>>>(
        x, seg_start, W1, b1, W2, part, N);
    combine_kernel<<<B, 128, 0, stream>>>(part, (float*)d_out);
}